// Round 16
// baseline (1430.599 us; speedup 1.0000x reference)
//
#include <hip/hip_runtime.h>

// ConvexPolytopeManifold: dual-PGD QP projection. B=4096, n=512, m=1024.
// Round 16 = round 15 with the A-LDS buffer-overlap bug fixed:
//   A tile = 32 rows x 32 shorts = 1024 shorts/buffer; r15 spaced buffers by
//   512 -> buf1 overlapped buf0 rows 16..31 (deterministic absmax 0.242).
//   Fix: A spacing 1024 (region [0,2048) shorts/wave; B at [2048,6144)).
// Barrier-free iteration GEMM: wave-private LDS, zero __syncthreads, BK=32,
// depth-2 pipeline self-synced with s_waitcnt vmcnt(6) (vmcnt(0) at tail).
// Setup/act/masked/final GEMMs stay on the proven r14 2-barrier kernel.
//
// math:
//   Q = A@A^T; y = x+u; c = y@A^T - b
//   lam1 = step*relu(c); 49x lam = relu(lam - 0.01*(lam@Q - c))
//   active = (c - lam@Q >= -TOL)
//   masked = (u@A^T) * active; lam1 = step*relu(masked)
//   9x lam = relu(lam - 0.01*(lam@Q - masked)) * active
//   out = u - lam@A

#define TOLV 1e-5f
#define STEPV 0.01f

typedef __attribute__((ext_vector_type(8))) _Float16 half8;
typedef __attribute__((ext_vector_type(4))) float floatx4;
typedef unsigned short ushort_t;

#define GLDS(gptr, lptr) \
    __builtin_amdgcn_global_load_lds( \
        (const __attribute__((address_space(1))) void*)(gptr), \
        (__attribute__((address_space(3))) void*)(lptr), 16, 0, 0)

// s_waitcnt imm (gfx9/CDNA): vmcnt[3:0] | expcnt[6:4] | lgkmcnt[11:8] | vmcnt[5:4]@[15:14]
#define WAIT_VM6() __builtin_amdgcn_s_waitcnt(0x0F70 | 6)   // vmcnt(6)
#define WAIT_VM0() __builtin_amdgcn_s_waitcnt(0x0F70 | 0)   // vmcnt(0)

__device__ inline ushort_t f2h(float f) {
    union { _Float16 h; ushort_t u; } c; c.h = (_Float16)f;   // RNE
    return c.u;
}
__device__ inline float h2f(ushort_t u) {
    union { ushort_t u; _Float16 h; } c; c.u = u;
    return (float)c.h;
}

__global__ void addcast_kernel(const float* __restrict__ x, const float* __restrict__ u,
                               ushort_t* __restrict__ yh, ushort_t* __restrict__ uh, int n) {
    int idx = (blockIdx.x * blockDim.x + threadIdx.x) * 4;
    if (idx < n) {
        float4 xv = *(const float4*)(x + idx);
        float4 uv = *(const float4*)(u + idx);
        ushort4 yo, uo;
        yo.x = f2h(xv.x + uv.x); yo.y = f2h(xv.y + uv.y);
        yo.z = f2h(xv.z + uv.z); yo.w = f2h(xv.w + uv.w);
        uo.x = f2h(uv.x); uo.y = f2h(uv.y); uo.z = f2h(uv.z); uo.w = f2h(uv.w);
        *(ushort4*)(yh + idx) = yo;
        *(ushort4*)(uh + idx) = uo;
    }
}

__global__ void cvt_h_kernel(const float* __restrict__ src, ushort_t* __restrict__ dst, int n) {
    int idx = (blockIdx.x * blockDim.x + threadIdx.x) * 4;
    if (idx < n) {
        float4 v = *(const float4*)(src + idx);
        ushort4 o;
        o.x = f2h(v.x); o.y = f2h(v.y); o.z = f2h(v.z); o.w = f2h(v.w);
        *(ushort4*)(dst + idx) = o;
    }
}

__global__ void transpose_cast_kernel(const float* __restrict__ A, ushort_t* __restrict__ AT,
                                      int m, int n) {
    __shared__ float t[32][33];
    int bx = blockIdx.x * 32;
    int by = blockIdx.y * 32;
    int tx = threadIdx.x & 31, ty = threadIdx.x >> 5;   // 32 x 8
#pragma unroll
    for (int i = 0; i < 32; i += 8)
        t[ty + i][tx] = A[(size_t)(by + ty + i) * n + bx + tx];
    __syncthreads();
#pragma unroll
    for (int i = 0; i < 32; i += 8)
        AT[(size_t)(bx + ty + i) * m + by + tx] = f2h(t[tx][ty + i]);
}

// ---------------- r14 2-barrier GEMM (setup / act / masked / final) ----------------
template<int EPI>
__global__ __launch_bounds__(256, 2)
void mfma_g(const ushort_t* __restrict__ X, const ushort_t* __restrict__ W,
            const ushort_t* __restrict__ lamIn, const float* __restrict__ cF,
            const ushort_t* __restrict__ cH, const ushort_t* __restrict__ actb,
            ushort_t* __restrict__ lamOut, float* __restrict__ cFout,
            ushort_t* __restrict__ cHout, ushort_t* __restrict__ actOut,
            const float* __restrict__ uin, float* __restrict__ outF,
            const float* __restrict__ bvec,
            int M, int N, int K) {
    __shared__ short As[2][64 * 64];
    __shared__ short Bs[2][128 * 64];

    const int tid = threadIdx.x;
    const int w = tid >> 6;
    const int lane = tid & 63;

    const int nbm = M >> 6;
    const int spx = nbm >> 3;
    const int xcd = blockIdx.x & 7;
    const int loc = blockIdx.x >> 3;
    const int bm = (xcd * spx + (loc % spx)) << 6;
    const int bn = (loc / spx) << 7;

    const int wm = (w & 1) * 32;
    const int wn = (w >> 1) * 64;
    const int quad = lane >> 4;
    const int l15 = lane & 15;

    const int ldr = lane >> 3;
    const int csw = ((lane & 7) ^ ldr) * 8;

    const ushort_t* Xb = X + (size_t)bm * K + csw;
    const ushort_t* Wb = W + (size_t)bn * K + csw;

    floatx4 acc[2][4] = {};
    const int KT = K >> 6;

#pragma unroll
    for (int t = 0; t < 2; ++t)
        GLDS(Xb + (size_t)(w * 16 + t * 8 + ldr) * K, As[0] + (w * 16 + t * 8) * 64);
#pragma unroll
    for (int t = 0; t < 4; ++t)
        GLDS(Wb + (size_t)(w * 32 + t * 8 + ldr) * K, Bs[0] + (w * 32 + t * 8) * 64);

    for (int kt = 0; kt < KT; ++kt) {
        __syncthreads();
        if (kt + 1 < KT) {
            const int nb = (kt + 1) & 1;
            const int ko = (kt + 1) << 6;
#pragma unroll
            for (int t = 0; t < 2; ++t)
                GLDS(Xb + (size_t)(w * 16 + t * 8 + ldr) * K + ko, As[nb] + (w * 16 + t * 8) * 64);
#pragma unroll
            for (int t = 0; t < 4; ++t)
                GLDS(Wb + (size_t)(w * 32 + t * 8 + ldr) * K + ko, Bs[nb] + (w * 32 + t * 8) * 64);
        }
        const int cb = kt & 1;
#pragma unroll
        for (int kk = 0; kk < 2; ++kk) {
            const int sw = ((kk * 4 + quad) ^ (l15 & 7)) * 8;
            half8 af[2], bfr[4];
#pragma unroll
            for (int i = 0; i < 2; ++i)
                af[i] = *(const half8*)(As[cb] + (wm + i * 16 + l15) * 64 + sw);
#pragma unroll
            for (int i = 0; i < 4; ++i)
                bfr[i] = *(const half8*)(Bs[cb] + (wn + i * 16 + l15) * 64 + sw);
#pragma unroll
            for (int mt = 0; mt < 2; ++mt)
#pragma unroll
                for (int nt = 0; nt < 4; ++nt)
                    acc[mt][nt] = __builtin_amdgcn_mfma_f32_16x16x32_f16(
                        af[mt], bfr[nt], acc[mt][nt], 0, 0, 0);
        }
    }

#pragma unroll
    for (int mt = 0; mt < 2; ++mt) {
#pragma unroll
        for (int nt = 0; nt < 4; ++nt) {
#pragma unroll
            for (int r = 0; r < 4; ++r) {
                int row = bm + wm + mt * 16 + quad * 4 + r;
                int col = bn + wn + nt * 16 + l15;
                size_t idx = (size_t)row * N + col;
                float v = acc[mt][nt][r];
                if (EPI == 0) {
                    lamOut[idx] = f2h(v);
                } else if (EPI == 1) {
                    float cv = v - bvec[col];
                    cFout[idx] = cv;
                    cHout[idx] = f2h(cv);
                    lamOut[idx] = f2h(STEPV * fmaxf(cv, 0.0f));
                } else if (EPI == 4) {
                    actOut[idx] = (cF[idx] - v >= -TOLV) ? (ushort_t)0x3C00 : (ushort_t)0;
                } else if (EPI == 5) {
                    float mv = v * h2f(actb[idx]);
                    cHout[idx] = f2h(mv);
                    lamOut[idx] = f2h(STEPV * fmaxf(mv, 0.0f));
                } else if (EPI == 6) {
                    outF[idx] = uin[idx] - v;
                }
            }
        }
    }
}

// ---------------- barrier-free iteration GEMM:  lamOut = f(X @ W^T) ----------------
// Wave-private LDS per wave (12 KB): A bufs [0,2048) shorts (1024 each),
// B bufs [2048,6144) shorts (2048 each). BK=32, depth-2 vmcnt pipeline.
// MASK=0: nv = relu(h2f(X) - step*(v - h2f(cH))); MASK=1: nv *= h2f(actb)
template<int MASK>
__global__ __launch_bounds__(256, 2)
void mfma_nb(const ushort_t* __restrict__ X, const ushort_t* __restrict__ W,
             const ushort_t* __restrict__ cH, const ushort_t* __restrict__ actb,
             ushort_t* __restrict__ lamOut,
             int M, int N, int K) {
    __shared__ short lds[24576];   // 4 waves x 6144 shorts

    const int tid = threadIdx.x;
    const int w = tid >> 6;
    const int lane = tid & 63;

    const int nbm = M >> 6;
    const int spx = nbm >> 3;
    const int xcd = blockIdx.x & 7;
    const int loc = blockIdx.x >> 3;
    const int bm = (xcd * spx + (loc % spx)) << 6;
    const int bn = (loc / spx) << 7;

    const int wm = (w & 1) * 32;
    const int wn = (w >> 1) * 64;
    const int quad = lane >> 4;
    const int l15 = lane & 15;

    short* wbase = lds + w * 6144;
    const int sr = lane >> 2;                       // row 0..15 in 16-row group
    const int kg = ((lane & 3) - (sr >> 1)) & 3;    // global chunk this lane fetches
    const ushort_t* Xs = X + (size_t)(bm + wm + sr) * K + kg * 8;
    const ushort_t* Ws = W + (size_t)(bn + wn + sr) * K + kg * 8;

    const int KT = K >> 5;       // BK=32
    floatx4 acc[2][4] = {};

    // stage(kt, buf): A 32 rows (2 issues), B 64 rows (4 issues); 6 loads total
    // A buf spacing 1024 shorts (FIX vs r15's 512); B buf spacing 2048.
#define STAGE(KT_IDX, BUF) do {                                              \
        const int _ko = (KT_IDX) << 5;                                       \
        GLDS(Xs + _ko,                   wbase + (BUF) * 1024);              \
        GLDS(Xs + (size_t)16 * K + _ko,  wbase + (BUF) * 1024 + 512);        \
        GLDS(Ws + _ko,                   wbase + 2048 + (BUF) * 2048);       \
        GLDS(Ws + (size_t)16 * K + _ko,  wbase + 2048 + (BUF) * 2048 + 512); \
        GLDS(Ws + (size_t)32 * K + _ko,  wbase + 2048 + (BUF) * 2048 + 1024);\
        GLDS(Ws + (size_t)48 * K + _ko,  wbase + 2048 + (BUF) * 2048 + 1536);\
    } while (0)

    STAGE(0, 0);
    STAGE(1, 1);

    const int rchunk = ((quad + (l15 >> 1)) & 3) * 8;   // phys chunk offset (shorts)

    for (int kt = 0; kt < KT; ++kt) {
        if (kt < KT - 1) WAIT_VM6(); else WAIT_VM0();

        const int cb = kt & 1;
        const short* Ab = wbase + cb * 1024;
        const short* Bb = wbase + 2048 + cb * 2048;

        half8 af[2], bfr[4];
#pragma unroll
        for (int i = 0; i < 2; ++i)
            af[i] = *(const half8*)(Ab + i * 512 + l15 * 32 + rchunk);
#pragma unroll
        for (int i = 0; i < 4; ++i)
            bfr[i] = *(const half8*)(Bb + i * 512 + l15 * 32 + rchunk);

#pragma unroll
        for (int mt = 0; mt < 2; ++mt)
#pragma unroll
            for (int nt = 0; nt < 4; ++nt)
                acc[mt][nt] = __builtin_amdgcn_mfma_f32_16x16x32_f16(
                    af[mt], bfr[nt], acc[mt][nt], 0, 0, 0);

        __builtin_amdgcn_sched_barrier(0);
        if (kt + 2 < KT) STAGE(kt + 2, cb);
        __builtin_amdgcn_sched_barrier(0);
    }
#undef STAGE

    // epilogue (C/D: row = quad*4+r, col = lane&15 per 16x16 tile)
#pragma unroll
    for (int mt = 0; mt < 2; ++mt) {
#pragma unroll
        for (int nt = 0; nt < 4; ++nt) {
#pragma unroll
            for (int r = 0; r < 4; ++r) {
                int row = bm + wm + mt * 16 + quad * 4 + r;
                int col = bn + wn + nt * 16 + l15;
                size_t idx = (size_t)row * N + col;
                float v = acc[mt][nt][r];
                float nv = fmaxf(fmaf(-STEPV, v - h2f(cH[idx]), h2f(X[idx])), 0.0f);
                if (MASK) nv *= h2f(actb[idx]);
                lamOut[idx] = f2h(nv);
            }
        }
    }
}

static inline int grid1d(int M, int N) { return (M >> 6) * (N >> 7); }

extern "C" void kernel_launch(void* const* d_in, const int* in_sizes, int n_in,
                              void* d_out, int out_size, void* d_ws, size_t ws_size,
                              hipStream_t stream) {
    const float* x = (const float*)d_in[0];  // [B,n]
    const float* u = (const float*)d_in[1];  // [B,n]
    const float* A = (const float*)d_in[2];  // [m,n]
    const float* b = (const float*)d_in[3];  // [m]
    float* out = (float*)d_out;              // [B,n]

    const int B = 4096, n = 512, m = 1024;
    const size_t Bm = (size_t)B * m;
    const size_t Bn = (size_t)B * n;

    ushort_t* A_h   = (ushort_t*)d_ws;             // [m,n]
    ushort_t* AT_h  = A_h + (size_t)m * n;         // [n,m]
    ushort_t* y_h   = AT_h + (size_t)n * m;        // [B,n]
    ushort_t* u_h   = y_h + Bn;                    // [B,n]
    ushort_t* Q_h   = u_h + Bn;                    // [m,m]
    ushort_t* lamA  = Q_h + (size_t)m * m;         // [B,m] fp16
    ushort_t* lamB  = lamA + Bm;                   // [B,m] fp16
    ushort_t* act   = lamB + Bm;                   // [B,m] fp16 0/1
    ushort_t* cHbuf = act + Bm;                    // [B,m] fp16 (c, then masked)
    float* cFbuf = (float*)(cHbuf + Bm);           // [B,m] f32 (c, for act test)

    dim3 blk(256);

    addcast_kernel<<<(int)(Bn / 4 + 255) / 256, 256, 0, stream>>>(x, u, y_h, u_h, (int)Bn);
    cvt_h_kernel<<<(m * n / 4 + 255) / 256, 256, 0, stream>>>(A, A_h, m * n);
    transpose_cast_kernel<<<dim3(n / 32, m / 32), dim3(256), 0, stream>>>(A, AT_h, m, n);

    // Q = fp16(A @ A^T)
    mfma_g<0><<<grid1d(m, m), blk, 0, stream>>>(
        A_h, A_h, nullptr, nullptr, nullptr, nullptr,
        Q_h, nullptr, nullptr, nullptr, nullptr, nullptr, nullptr, m, m, n);

    // c = y@A^T - b (cF fp32 + cH fp16); lamA = fp16(lam1 = step*relu(c))
    mfma_g<1><<<grid1d(B, m), blk, 0, stream>>>(
        y_h, A_h, nullptr, nullptr, nullptr, nullptr,
        lamA, cFbuf, cHbuf, nullptr, nullptr, nullptr, b, B, m, n);

    // phase 1: 49 more iterations (barrier-free kernel)
    ushort_t* lin = lamA; ushort_t* lout = lamB;
    for (int it = 0; it < 49; ++it) {
        mfma_nb<0><<<grid1d(B, m), blk, 0, stream>>>(
            lin, Q_h, cHbuf, nullptr, lout, B, m, m);
        ushort_t* t = lin; lin = lout; lout = t;
    }

    // active = (c - lam50@Q >= -TOL)
    mfma_g<4><<<grid1d(B, m), blk, 0, stream>>>(
        lin, Q_h, nullptr, cFbuf, nullptr, nullptr,
        nullptr, nullptr, nullptr, act, nullptr, nullptr, nullptr, B, m, m);

    // masked = (u@A^T)*active -> cHbuf; lamA = fp16(lam1 = step*relu(masked))
    mfma_g<5><<<grid1d(B, m), blk, 0, stream>>>(
        u_h, A_h, nullptr, nullptr, nullptr, act,
        lamA, nullptr, cHbuf, nullptr, nullptr, nullptr, nullptr, B, m, n);

    // phase 2: 9 more iterations
    lin = lamA; lout = lamB;
    for (int it = 0; it < 9; ++it) {
        mfma_nb<1><<<grid1d(B, m), blk, 0, stream>>>(
            lin, Q_h, cHbuf, act, lout, B, m, m);
        ushort_t* t = lin; lin = lout; lout = t;
    }

    // out = u - lam @ A
    mfma_g<6><<<grid1d(B, n), blk, 0, stream>>>(
        lin, AT_h, nullptr, nullptr, nullptr, nullptr,
        nullptr, nullptr, nullptr, nullptr, u, out, nullptr, B, n, m);
}

// Round 17
// 1172.534 us; speedup vs baseline: 1.2201x; 1.2201x over previous
//
#include <hip/hip_runtime.h>

// ConvexPolytopeManifold: dual-PGD QP projection. B=4096, n=512, m=1024.
// Round 17: RESTORE round-14 (best measured: 1175/1182 us, reproduced twice).
// Structural alternatives all lost to it:
//   r12 128x128 tile  -> 1407 (1 wave/SIMD occupancy trap)
//   r13 direct-A frags-> 41455 (strided gathers, vmcnt serialization)
//   r9  coop persist  -> 4060 (grid.sync L2 flush, 402MB HBM/dispatch)
//   r16 barrier-free  -> 1430 (wave-private staging duplicates B; BK=32
//                              halves stage amortization; sched_barrier pins)
// Remaining gap to composed LDS/L2 floor (~10-12 us/iter vs 17 measured) is
// the structural 2-barrier drain (m97-class); closing it needs hand-asm-grade
// K-loop scheduling (hipBLASLt-style), out of scope here.
// Structure: full fp16 pipeline (f16 MFMA = bf16 rate, 8x lower rounding);
// single fp16 lam = master AND operand; 64Mx128N tile, 4 waves, wave tile
// 32x64; double-buffered LDS staging; XOR bank swizzle; XCD-aware 1D grid;
// per-iteration dispatch loop; first PGD step of each phase folded into the
// c/masked epilogues.
//
// math:
//   Q = A@A^T; y = x+u; c = y@A^T - b
//   lam1 = step*relu(c); 49x lam = relu(lam - 0.01*(lam@Q - c))
//   active = (c - lam@Q >= -TOL)
//   masked = (u@A^T) * active; lam1 = step*relu(masked)
//   9x lam = relu(lam - 0.01*(lam@Q - masked)) * active
//   out = u - lam@A

#define TOLV 1e-5f
#define STEPV 0.01f

typedef __attribute__((ext_vector_type(8))) _Float16 half8;
typedef __attribute__((ext_vector_type(4))) float floatx4;
typedef unsigned short ushort_t;

#define GLDS(gptr, lptr) \
    __builtin_amdgcn_global_load_lds( \
        (const __attribute__((address_space(1))) void*)(gptr), \
        (__attribute__((address_space(3))) void*)(lptr), 16, 0, 0)

__device__ inline ushort_t f2h(float f) {
    union { _Float16 h; ushort_t u; } c; c.h = (_Float16)f;   // RNE
    return c.u;
}
__device__ inline float h2f(ushort_t u) {
    union { ushort_t u; _Float16 h; } c; c.u = u;
    return (float)c.h;
}

__global__ void addcast_kernel(const float* __restrict__ x, const float* __restrict__ u,
                               ushort_t* __restrict__ yh, ushort_t* __restrict__ uh, int n) {
    int idx = (blockIdx.x * blockDim.x + threadIdx.x) * 4;
    if (idx < n) {
        float4 xv = *(const float4*)(x + idx);
        float4 uv = *(const float4*)(u + idx);
        ushort4 yo, uo;
        yo.x = f2h(xv.x + uv.x); yo.y = f2h(xv.y + uv.y);
        yo.z = f2h(xv.z + uv.z); yo.w = f2h(xv.w + uv.w);
        uo.x = f2h(uv.x); uo.y = f2h(uv.y); uo.z = f2h(uv.z); uo.w = f2h(uv.w);
        *(ushort4*)(yh + idx) = yo;
        *(ushort4*)(uh + idx) = uo;
    }
}

__global__ void cvt_h_kernel(const float* __restrict__ src, ushort_t* __restrict__ dst, int n) {
    int idx = (blockIdx.x * blockDim.x + threadIdx.x) * 4;
    if (idx < n) {
        float4 v = *(const float4*)(src + idx);
        ushort4 o;
        o.x = f2h(v.x); o.y = f2h(v.y); o.z = f2h(v.z); o.w = f2h(v.w);
        *(ushort4*)(dst + idx) = o;
    }
}

__global__ void transpose_cast_kernel(const float* __restrict__ A, ushort_t* __restrict__ AT,
                                      int m, int n) {
    __shared__ float t[32][33];
    int bx = blockIdx.x * 32;
    int by = blockIdx.y * 32;
    int tx = threadIdx.x & 31, ty = threadIdx.x >> 5;   // 32 x 8
#pragma unroll
    for (int i = 0; i < 32; i += 8)
        t[ty + i][tx] = A[(size_t)(by + ty + i) * n + bx + tx];
    __syncthreads();
#pragma unroll
    for (int i = 0; i < 32; i += 8)
        AT[(size_t)(bx + ty + i) * m + by + tx] = f2h(t[tx][ty + i]);
}

// ---------------- fp16 MFMA GEMM, double-buffered:  C = X @ W^T ----------------
// X=[M,K] fp16, W=[N,K] fp16. 256 thr = 4 waves. Tile 64Mx128N, BK=64,
// wave tile 32x64 (2x4 of 16x16x32 f16). XOR-swizzled LDS; XCD-aware 1D grid.
// EPI: 0 Q:      lamOut = fp16(v)
//      1 c+lam1: cv=v-bvec[col]; cFout=cv; cHout=f2h(cv); lamOut=f2h(step*relu(cv))
//      2 iter:   nv=relu(h2f(lamIn) - step*(v - h2f(cH))); lamOut=f2h(nv)
//      3 iter*act
//      4 act:    actOut = (cF - v >= -TOL) ? 1 : 0  (fp16)
//      5 masked+lam1: mv=v*act; cHout=f2h(mv); lamOut=f2h(step*relu(mv))
//      6 final:  outF = uin - v
template<int EPI>
__global__ __launch_bounds__(256, 2)
void mfma_g(const ushort_t* __restrict__ X, const ushort_t* __restrict__ W,
            const ushort_t* __restrict__ lamIn, const float* __restrict__ cF,
            const ushort_t* __restrict__ cH, const ushort_t* __restrict__ actb,
            ushort_t* __restrict__ lamOut, float* __restrict__ cFout,
            ushort_t* __restrict__ cHout, ushort_t* __restrict__ actOut,
            const float* __restrict__ uin, float* __restrict__ outF,
            const float* __restrict__ bvec,
            int M, int N, int K) {
    __shared__ short As[2][64 * 64];     // 2 x  8 KB
    __shared__ short Bs[2][128 * 64];    // 2 x 16 KB

    const int tid = threadIdx.x;
    const int w = tid >> 6;
    const int lane = tid & 63;

    const int nbm = M >> 6;
    const int spx = nbm >> 3;
    const int xcd = blockIdx.x & 7;
    const int loc = blockIdx.x >> 3;
    const int bm = (xcd * spx + (loc % spx)) << 6;
    const int bn = (loc / spx) << 7;

    const int wm = (w & 1) * 32;
    const int wn = (w >> 1) * 64;
    const int quad = lane >> 4;
    const int l15 = lane & 15;

    const int ldr = lane >> 3;
    const int csw = ((lane & 7) ^ ldr) * 8;

    const ushort_t* Xb = X + (size_t)bm * K + csw;
    const ushort_t* Wb = W + (size_t)bn * K + csw;

    floatx4 acc[2][4] = {};

    const int KT = K >> 6;

    // prologue: stage K-tile 0 into buffer 0
#pragma unroll
    for (int t = 0; t < 2; ++t)
        GLDS(Xb + (size_t)(w * 16 + t * 8 + ldr) * K, As[0] + (w * 16 + t * 8) * 64);
#pragma unroll
    for (int t = 0; t < 4; ++t)
        GLDS(Wb + (size_t)(w * 32 + t * 8 + ldr) * K, Bs[0] + (w * 32 + t * 8) * 64);

    for (int kt = 0; kt < KT; ++kt) {
        __syncthreads();   // drains async stage for kt

        if (kt + 1 < KT) {
            const int nb = (kt + 1) & 1;
            const int ko = (kt + 1) << 6;
#pragma unroll
            for (int t = 0; t < 2; ++t)
                GLDS(Xb + (size_t)(w * 16 + t * 8 + ldr) * K + ko, As[nb] + (w * 16 + t * 8) * 64);
#pragma unroll
            for (int t = 0; t < 4; ++t)
                GLDS(Wb + (size_t)(w * 32 + t * 8 + ldr) * K + ko, Bs[nb] + (w * 32 + t * 8) * 64);
        }

        const int cb = kt & 1;
#pragma unroll
        for (int kk = 0; kk < 2; ++kk) {
            const int sw = ((kk * 4 + quad) ^ (l15 & 7)) * 8;
            half8 af[2], bfr[4];
#pragma unroll
            for (int i = 0; i < 2; ++i)
                af[i] = *(const half8*)(As[cb] + (wm + i * 16 + l15) * 64 + sw);
#pragma unroll
            for (int i = 0; i < 4; ++i)
                bfr[i] = *(const half8*)(Bs[cb] + (wn + i * 16 + l15) * 64 + sw);
#pragma unroll
            for (int mt = 0; mt < 2; ++mt)
#pragma unroll
                for (int nt = 0; nt < 4; ++nt)
                    acc[mt][nt] = __builtin_amdgcn_mfma_f32_16x16x32_f16(
                        af[mt], bfr[nt], acc[mt][nt], 0, 0, 0);
        }
    }

    // C/D layout: row = quad*4 + r, col = lane&15 within each 16x16 tile
#pragma unroll
    for (int mt = 0; mt < 2; ++mt) {
#pragma unroll
        for (int nt = 0; nt < 4; ++nt) {
#pragma unroll
            for (int r = 0; r < 4; ++r) {
                int row = bm + wm + mt * 16 + quad * 4 + r;
                int col = bn + wn + nt * 16 + l15;
                size_t idx = (size_t)row * N + col;
                float v = acc[mt][nt][r];
                if (EPI == 0) {
                    lamOut[idx] = f2h(v);
                } else if (EPI == 1) {
                    float cv = v - bvec[col];
                    cFout[idx] = cv;
                    cHout[idx] = f2h(cv);
                    lamOut[idx] = f2h(STEPV * fmaxf(cv, 0.0f));
                } else if (EPI == 2) {
                    float nv = fmaxf(fmaf(-STEPV, v - h2f(cH[idx]), h2f(lamIn[idx])), 0.0f);
                    lamOut[idx] = f2h(nv);
                } else if (EPI == 3) {
                    float nv = fmaxf(fmaf(-STEPV, v - h2f(cH[idx]), h2f(lamIn[idx])), 0.0f);
                    nv *= h2f(actb[idx]);
                    lamOut[idx] = f2h(nv);
                } else if (EPI == 4) {
                    actOut[idx] = (cF[idx] - v >= -TOLV) ? (ushort_t)0x3C00 : (ushort_t)0;
                } else if (EPI == 5) {
                    float mv = v * h2f(actb[idx]);
                    cHout[idx] = f2h(mv);
                    lamOut[idx] = f2h(STEPV * fmaxf(mv, 0.0f));
                } else if (EPI == 6) {
                    outF[idx] = uin[idx] - v;
                }
            }
        }
    }
}

static inline int grid1d(int M, int N) { return (M >> 6) * (N >> 7); }

extern "C" void kernel_launch(void* const* d_in, const int* in_sizes, int n_in,
                              void* d_out, int out_size, void* d_ws, size_t ws_size,
                              hipStream_t stream) {
    const float* x = (const float*)d_in[0];  // [B,n]
    const float* u = (const float*)d_in[1];  // [B,n]
    const float* A = (const float*)d_in[2];  // [m,n]
    const float* b = (const float*)d_in[3];  // [m]
    float* out = (float*)d_out;              // [B,n]

    const int B = 4096, n = 512, m = 1024;
    const size_t Bm = (size_t)B * m;
    const size_t Bn = (size_t)B * n;

    ushort_t* A_h   = (ushort_t*)d_ws;             // [m,n]
    ushort_t* AT_h  = A_h + (size_t)m * n;         // [n,m]
    ushort_t* y_h   = AT_h + (size_t)n * m;        // [B,n]
    ushort_t* u_h   = y_h + Bn;                    // [B,n]
    ushort_t* Q_h   = u_h + Bn;                    // [m,m]
    ushort_t* lamA  = Q_h + (size_t)m * m;         // [B,m] fp16
    ushort_t* lamB  = lamA + Bm;                   // [B,m] fp16
    ushort_t* act   = lamB + Bm;                   // [B,m] fp16 0/1
    ushort_t* cHbuf = act + Bm;                    // [B,m] fp16 (c, then masked)
    float* cFbuf = (float*)(cHbuf + Bm);           // [B,m] f32 (c, for act test)

    dim3 blk(256);

    addcast_kernel<<<(int)(Bn / 4 + 255) / 256, 256, 0, stream>>>(x, u, y_h, u_h, (int)Bn);
    cvt_h_kernel<<<(m * n / 4 + 255) / 256, 256, 0, stream>>>(A, A_h, m * n);
    transpose_cast_kernel<<<dim3(n / 32, m / 32), dim3(256), 0, stream>>>(A, AT_h, m, n);

    // Q = fp16(A @ A^T)
    mfma_g<0><<<grid1d(m, m), blk, 0, stream>>>(
        A_h, A_h, nullptr, nullptr, nullptr, nullptr,
        Q_h, nullptr, nullptr, nullptr, nullptr, nullptr, nullptr, m, m, n);

    // c = y@A^T - b (cF fp32 + cH fp16); lamA = fp16(lam1 = step*relu(c))
    mfma_g<1><<<grid1d(B, m), blk, 0, stream>>>(
        y_h, A_h, nullptr, nullptr, nullptr, nullptr,
        lamA, cFbuf, cHbuf, nullptr, nullptr, nullptr, b, B, m, n);

    // phase 1: 49 more iterations (lam fp16 ping-pong)
    ushort_t* lin = lamA; ushort_t* lout = lamB;
    for (int it = 0; it < 49; ++it) {
        mfma_g<2><<<grid1d(B, m), blk, 0, stream>>>(
            lin, Q_h, lin, nullptr, cHbuf, nullptr,
            lout, nullptr, nullptr, nullptr, nullptr, nullptr, nullptr, B, m, m);
        ushort_t* t = lin; lin = lout; lout = t;
    }

    // active = (c - lam50@Q >= -TOL)
    mfma_g<4><<<grid1d(B, m), blk, 0, stream>>>(
        lin, Q_h, nullptr, cFbuf, nullptr, nullptr,
        nullptr, nullptr, nullptr, act, nullptr, nullptr, nullptr, B, m, m);

    // masked = (u@A^T)*active -> cHbuf; lamA = fp16(lam1 = step*relu(masked))
    mfma_g<5><<<grid1d(B, m), blk, 0, stream>>>(
        u_h, A_h, nullptr, nullptr, nullptr, act,
        lamA, nullptr, cHbuf, nullptr, nullptr, nullptr, nullptr, B, m, n);

    // phase 2: 9 more iterations
    lin = lamA; lout = lamB;
    for (int it = 0; it < 9; ++it) {
        mfma_g<3><<<grid1d(B, m), blk, 0, stream>>>(
            lin, Q_h, lin, nullptr, cHbuf, act,
            lout, nullptr, nullptr, nullptr, nullptr, nullptr, nullptr, B, m, m);
        ushort_t* t = lin; lin = lout; lout = t;
    }

    // out = u - lam @ A
    mfma_g<6><<<grid1d(B, n), blk, 0, stream>>>(
        lin, AT_h, nullptr, nullptr, nullptr, nullptr,
        nullptr, nullptr, nullptr, nullptr, u, out, nullptr, B, n, m);
}